// Round 1
// baseline (276.060 us; speedup 1.0000x reference)
//
#include <hip/hip_runtime.h>

#define B_    4
#define N_OBJ 24
#define C_    256
#define H_    100
#define W_    100
#define HW_   (H_ * W_)
#define OUT_  7
#define P_    276              // N*(N-1)/2
#define M_    (N_OBJ + P_)     // 300 rois per batch
#define SCALE_ 0.25f
#define CHW_OUT (C_ * OUT_ * OUT_)   // 12544 floats per roi-slot chunk

__device__ __forceinline__ void pair_from_p(int p, int& i, int& j) {
    int ii = 0, rem = p;
    while (rem >= N_OBJ - 1 - ii) { rem -= (N_OBJ - 1 - ii); ++ii; }
    i = ii; j = ii + 1 + rem;
}

// ---------------------------------------------------------------- transpose
// feat [B,C,H,W] -> featT [B,H*W,C]
__global__ __launch_bounds__(256) void transpose_kernel(
        const float* __restrict__ feat, float* __restrict__ featT) {
    __shared__ float tile[64][65];
    const int b   = blockIdx.z;
    const int c0  = blockIdx.y * 64;
    const int px0 = blockIdx.x * 64;
    const int t   = threadIdx.x;
    const int cl  = t >> 6;   // 0..3
    const int px  = t & 63;
#pragma unroll
    for (int k = 0; k < 16; ++k) {
        const int c_loc = cl + k * 4;
        const int gpx   = px0 + px;
        tile[c_loc][px] = (gpx < HW_)
            ? feat[((size_t)b * C_ + c0 + c_loc) * HW_ + gpx] : 0.0f;
    }
    __syncthreads();
    const int c2 = t & 63;
    const int pl = t >> 6;
#pragma unroll
    for (int k = 0; k < 16; ++k) {
        const int px_l = pl + k * 4;
        const int gpx  = px0 + px_l;
        if (gpx < HW_)
            featT[((size_t)b * HW_ + gpx) * C_ + c0 + c2] = tile[c2][px_l];
    }
}

// ---------------------------------------------------------------- roi align
// One block (4 waves) per roi. Lane covers 4 channels (float4), wave covers a
// bin. LDS tile [c][s] converts channel-last compute into channel-major out.
__global__ __launch_bounds__(256) void roi_kernel(
        const float* __restrict__ featT,   // [B, HW, C]
        const float* __restrict__ boxes,   // [B, N, 4]
        float* __restrict__ out,           // [B*P, 3, C, 49]
        float* __restrict__ ws_obj) {      // [B, N, C, 49]
    __shared__ float lds[CHW_OUT];         // 49 KiB
    const int r = blockIdx.x;
    const int b = r / M_;
    const int m = r - b * M_;

    float x1, y1, x2, y2;
    if (m < N_OBJ) {
        const float* bp = boxes + ((size_t)b * N_OBJ + m) * 4;
        x1 = bp[0]; y1 = bp[1]; x2 = bp[2]; y2 = bp[3];
    } else {
        int i, j; pair_from_p(m - N_OBJ, i, j);
        const float* b1 = boxes + ((size_t)b * N_OBJ + i) * 4;
        const float* b2 = boxes + ((size_t)b * N_OBJ + j) * 4;
        x1 = fminf(b1[0], b2[0]); y1 = fminf(b1[1], b2[1]);
        x2 = fmaxf(b1[2], b2[2]); y2 = fmaxf(b1[3], b2[3]);
    }
    x1 *= SCALE_; y1 *= SCALE_; x2 *= SCALE_; y2 *= SCALE_;
    const float roi_w = fmaxf(x2 - x1, 1.0f);
    const float roi_h = fmaxf(y2 - y1, 1.0f);
    const float bin_w = roi_w * (1.0f / OUT_);
    const float bin_h = roi_h * (1.0f / OUT_);

    const int lane = threadIdx.x & 63;
    const int wv   = threadIdx.x >> 6;
    const float4* fbase = (const float4*)(featT + (size_t)b * HW_ * C_) + lane;

    for (int s = wv; s < OUT_ * OUT_; s += 4) {
        const int ph = s / OUT_, pw = s - ph * OUT_;
        float4 acc = make_float4(0.f, 0.f, 0.f, 0.f);
#pragma unroll
        for (int iy = 0; iy < 2; ++iy) {
            const float Y  = y1 + ((float)ph + (iy ? 0.75f : 0.25f)) * bin_h;
            const bool vy  = (Y > -1.0f) && (Y < (float)H_);
            const float Yc = fminf(fmaxf(Y, 0.0f), (float)(H_ - 1));
            const int  y0  = (int)floorf(Yc);
            const float ly = Yc - (float)y0;
            const float hy = 1.0f - ly;
            const int  y1i = min(y0 + 1, H_ - 1);
#pragma unroll
            for (int ix = 0; ix < 2; ++ix) {
                const float X  = x1 + ((float)pw + (ix ? 0.75f : 0.25f)) * bin_w;
                const bool vx  = (X > -1.0f) && (X < (float)W_);
                const float Xc = fminf(fmaxf(X, 0.0f), (float)(W_ - 1));
                const int  x0  = (int)floorf(Xc);
                const float lx = Xc - (float)x0;
                const float hx = 1.0f - lx;
                const int  x1i = min(x0 + 1, W_ - 1);
                const float vs = (vy && vx) ? 0.25f : 0.0f;  // mean over 4 samples
                const float w00 = vs * hy * hx, w01 = vs * hy * lx;
                const float w10 = vs * ly * hx, w11 = vs * ly * lx;
                const float4 f00 = fbase[(y0  * W_ + x0 ) * (C_ / 4)];
                const float4 f01 = fbase[(y0  * W_ + x1i) * (C_ / 4)];
                const float4 f10 = fbase[(y1i * W_ + x0 ) * (C_ / 4)];
                const float4 f11 = fbase[(y1i * W_ + x1i) * (C_ / 4)];
                acc.x += w00 * f00.x + w01 * f01.x + w10 * f10.x + w11 * f11.x;
                acc.y += w00 * f00.y + w01 * f01.y + w10 * f10.y + w11 * f11.y;
                acc.z += w00 * f00.z + w01 * f01.z + w10 * f10.z + w11 * f11.z;
                acc.w += w00 * f00.w + w01 * f01.w + w10 * f10.w + w11 * f11.w;
            }
        }
        const int c0 = lane * 4;
        lds[(c0 + 0) * 49 + s] = acc.x;
        lds[(c0 + 1) * 49 + s] = acc.y;
        lds[(c0 + 2) * 49 + s] = acc.z;
        lds[(c0 + 3) * 49 + s] = acc.w;
    }
    __syncthreads();

    float* dst = (m < N_OBJ)
        ? (ws_obj + ((size_t)b * N_OBJ + m) * CHW_OUT)
        : (out + (((size_t)(b * P_ + (m - N_OBJ))) * 3 + 2) * CHW_OUT);
    const float4* s4 = (const float4*)lds;
    float4* d4 = (float4*)dst;
    for (int idx = threadIdx.x; idx < CHW_OUT / 4; idx += 256)
        d4[idx] = s4[idx];
}

// ---------------------------------------------------------------- assemble
// Fan object pooled tiles out to pair slots 0 (i) and 1 (j).
__global__ __launch_bounds__(256) void assemble_kernel(
        const float* __restrict__ ws_obj, float* __restrict__ out) {
    const int bp   = blockIdx.x;          // 0 .. B*P-1
    const int slot = blockIdx.y;          // 0 or 1
    const int b = bp / P_;
    const int p = bp - b * P_;
    int i, j; pair_from_p(p, i, j);
    const int n = slot ? j : i;
    const float4* src = (const float4*)(ws_obj + ((size_t)b * N_OBJ + n) * CHW_OUT);
    float4* dst = (float4*)(out + (((size_t)bp) * 3 + slot) * CHW_OUT);
    for (int idx = threadIdx.x; idx < CHW_OUT / 4; idx += 256)
        dst[idx] = src[idx];
}

extern "C" void kernel_launch(void* const* d_in, const int* in_sizes, int n_in,
                              void* d_out, int out_size, void* d_ws, size_t ws_size,
                              hipStream_t stream) {
    const float* feat  = (const float*)d_in[0];   // [B,C,H,W] fp32
    const float* boxes = (const float*)d_in[1];   // [B,N,4]  fp32
    float* out = (float*)d_out;                   // [B*P,3,C,7,7] fp32

    float* featT  = (float*)d_ws;                          // B*HW*C floats (~41 MB)
    float* ws_obj = featT + (size_t)B_ * HW_ * C_;         // B*N*C*49 (~4.8 MB)

    transpose_kernel<<<dim3((HW_ + 63) / 64, C_ / 64, B_), 256, 0, stream>>>(feat, featT);
    roi_kernel<<<B_ * M_, 256, 0, stream>>>(featT, boxes, out, ws_obj);
    assemble_kernel<<<dim3(B_ * P_, 2), 256, 0, stream>>>(ws_obj, out);
}